// Round 13
// baseline (105.246 us; speedup 1.0000x reference)
//
#include <hip/hip_runtime.h>
#include <math.h>

#define BB 64
#define WW 128   // K (input feature dim per node)
#define FF 64    // nodes
#define HH 4
#define OW 128   // D (per-head output dim)

// ---------------------------------------------------------------------------
// Fully fused GAT, v12 = v9 economics + k-split 1024-thread phase A.
// v11 post-mortem: 8i tile doubled x-load instrs + spilled (WRITE 13.3MB,
// VGPR 128) -> 56us. Reverted. v9 wall: VALU 49K + LDS 53K ~= 100K cyc,
// ~50% overlap at 2 waves/SIMD in A.
// v12 insight: A's total ds_read count = Td*T/2, independent of T at fixed
// Td. So 1024 threads with kh-split (each half does 64 k, tile 4i x 8d)
// keeps wv = 2048 and x-loads = 1024 EXACTLY equal to v9, halves per-thread
// serial work, and doubles A to 4 waves/SIMD. Partials combined through a
// conflict-free stride-36 LDS exchange (~128 wave-instrs, 2 barriers).
// B/C/D/E/F = v9 verbatim on the lower 512 threads (internal barriers
// lifted to uniform control flow; upper waves idle there).
// Revert trigger: WRITE >= 20MB (spill) -> v9 final.
// ---------------------------------------------------------------------------

struct GemmRegion {
    float wq[2 * 2 * 128 * 68]; // [(kh*256 + m*128 + d)][k 64 pad 68] 139 KB
};
struct AttnRegion {
    float fsl[FF * 132];        // [i][d] pad 132
    float fdl[FF * 132];        // [j][d] pad 132
    float stT[FF * 68];         // [j][i] pad 68  (TRANSPOSED scores)
    float st2[FF * 68];         // [i][j] pad 68  (D partial exchange)
    float A6[OW], B4[OW];       // 0.6*a_d, 0.4*a_d
    float redm[4 * 64];         // C: cs/cd partials
    float invl[64];             // 0.25 / l_j
    float xfer[256 * 36];       // F: i-half partial exchange (36.9 KB)
};
struct ExRegion {               // A-phase kh-partial exchange:
    float pad[FF * 132 * 2];    //   overlays fsl+fdl (NOT touched)
    float ex[512 * 36];         //   overlays stT..xfer (dead at that time)
};
union SMem { GemmRegion g; AttnRegion a; ExRegion e; };

__global__ void __launch_bounds__(1024)
gat_fused(
    const float* __restrict__ x,     // [B][128 k][64 i]
    const float* __restrict__ Wsrc,  // [512][128]
    const float* __restrict__ bsrc,
    const float* __restrict__ Wdst,
    const float* __restrict__ bdst,
    const float* __restrict__ attn,  // [H][128]
    float* __restrict__ out)         // [B][128 d][64 j], pre-zeroed
{
    __shared__ __align__(16) SMem sm;
    __shared__ float bl[2 * 128];

    const int bx = blockIdx.x;
    const int h  = bx & 3;
    const int b  = bx >> 2;
    const int t  = threadIdx.x;

    // ---- phase A map (1024): kh | m | ig(16 x 4 rows) | dg(16 -> 8 d) ----
    // thread: k-half kh, rows i = ig*4..+3 of (m ? fd : fs), d = dg + 16e.
    const int kh   = t >> 9;
    const int rem9 = t & 511;
    const int m    = rem9 >> 8;
    const int ig   = (rem9 >> 4) & 15;
    const int dg   = rem9 & 15;
    const int i0   = ig * 4;

    if (t < 256) bl[t] = (t & 128 ? bdst : bsrc)[h * 128 + (t & 127)];

    const float* xb = x + (size_t)b * (WW * FF);   // [128 k][64 node]

    // ---- stage BOTH W k-halves: 8192 float4, 8 per thread ----
    #pragma unroll
    for (int p = 0; p < 8; ++p) {
        const int idx = p * 1024 + t;           // [kh 2][mm 2][d 128][q 16]
        const int k2 = idx >> 12;
        const int mm = (idx >> 11) & 1;
        const int d  = (idx >> 4) & 127;
        const int q  = idx & 15;
        *(float4*)&sm.g.wq[((k2 << 8) + mm * 128 + d) * 68 + q * 4] =
            *(const float4*)((mm ? Wdst : Wsrc)
                             + (size_t)(h * 128 + d) * WW + k2 * 64 + q * 4);
    }
    __syncthreads();

    float acc[4][8] = {};            // [ii][e]
    {
        const int wbase = (kh << 8) + m * 128 + dg;   // + 16*e
        const float* xk = xb + (size_t)(kh * 64) * FF;
        #pragma unroll 2
        for (int k0 = 0; k0 < 64; k0 += 4) {
            float4 wv[8];
            #pragma unroll
            for (int e = 0; e < 8; ++e)
                wv[e] = *(const float4*)&sm.g.wq[(wbase + 16 * e) * 68 + k0];
            #pragma unroll
            for (int kk = 0; kk < 4; ++kk) {
                const float4 xv = *(const float4*)(xk + (size_t)(k0 + kk) * FF + i0);
                #pragma unroll
                for (int e = 0; e < 8; ++e) {
                    const float wf = ((const float*)&wv[e])[kk];
                    acc[0][e] = fmaf(xv.x, wf, acc[0][e]);
                    acc[1][e] = fmaf(xv.y, wf, acc[1][e]);
                    acc[2][e] = fmaf(xv.z, wf, acc[2][e]);
                    acc[3][e] = fmaf(xv.w, wf, acc[3][e]);
                }
            }
        }
    }
    __syncthreads();   // wq dead

    // ---- kh-partial exchange: kh1 writes ex (stride 36: conflict-free) ----
    if (kh) {
        #pragma unroll
        for (int ii = 0; ii < 4; ++ii) {
            float4 a0 = {acc[ii][0], acc[ii][1], acc[ii][2], acc[ii][3]};
            float4 a1 = {acc[ii][4], acc[ii][5], acc[ii][6], acc[ii][7]};
            *(float4*)&sm.e.ex[rem9 * 36 + ii * 8]     = a0;
            *(float4*)&sm.e.ex[rem9 * 36 + ii * 8 + 4] = a1;
        }
    }
    __syncthreads();

    // ---- phase B: kh0 combines partials + bias -> fsl/fdl ----
    if (!kh) {
        float* dst = m ? sm.a.fdl : sm.a.fsl;
        #pragma unroll
        for (int ii = 0; ii < 4; ++ii) {
            const float4 p0 = *(const float4*)&sm.e.ex[rem9 * 36 + ii * 8];
            const float4 p1 = *(const float4*)&sm.e.ex[rem9 * 36 + ii * 8 + 4];
            const float* pp0 = (const float*)&p0;
            const float* pp1 = (const float*)&p1;
            #pragma unroll
            for (int e = 0; e < 8; ++e) {
                const int d = dg + 16 * e;
                const float pv = (e < 4) ? pp0[e] : pp1[e - 4];
                dst[(i0 + ii) * 132 + d] = acc[ii][e] + pv + bl[m * 128 + d];
            }
        }
    }
    __syncthreads();   // ex dead; A6/B4 area safe to write now

    if (t < 128) {
        const float av = attn[h * OW + t];
        sm.a.A6[t] = 0.6f * av;
        sm.a.B4[t] = 0.4f * av;
    }
    __syncthreads();

    // --------- phase C: cs/cd partials (256 threads, 2 halves each) ------
    if (t < 256) {
        const int i = t & 63, sel = t >> 6;
        const float* src = (sel < 2 ? sm.a.fsl : sm.a.fdl) + i * 132 + (sel & 1) * 64;
        const float* a6  = sm.a.A6 + (sel & 1) * 64;
        float s = 0.0f;
        #pragma unroll
        for (int c = 0; c < 16; ++c) {
            float4 fv = *(const float4*)&src[c * 4];
            float4 av = *(const float4*)&a6[c * 4];
            s = fmaf(fv.x, av.x, fmaf(fv.y, av.y, fmaf(fv.z, av.z, fmaf(fv.w, av.w, s))));
        }
        sm.a.redm[sel * 64 + i] = s;
    }
    __syncthreads();

    // -------- phase D: scores on t<512, 2-D tile 4i x 4j, d-split --------
    {
        const bool act = t < 512;
        const int dh  = (t >> 8) & 1;
        const int rem = t & 255;
        const int iT  = rem & 15;
        const int j0D = (rem >> 4) * 4;
        float4 scq[4];                   // [ii]; components = jj
        scq[0] = scq[1] = scq[2] = scq[3] = float4{0.f, 0.f, 0.f, 0.f};
        if (act) {
            const int cBase = dh * 16;
            #pragma unroll 4
            for (int c = 0; c < 16; ++c) {
                const int dd0 = (cBase + c) * 4;
                const float4 b4 = *(const float4*)&sm.a.B4[dd0];
                float4 fdv[4];
                #pragma unroll
                for (int jj = 0; jj < 4; ++jj)
                    fdv[jj] = *(const float4*)&sm.a.fdl[(j0D + jj) * 132 + dd0];
                #pragma unroll
                for (int ii = 0; ii < 4; ++ii) {
                    const float4 fsv =
                        *(const float4*)&sm.a.fsl[(iT + 16 * ii) * 132 + dd0];
                    float* sc = (float*)&scq[ii];
                    #pragma unroll
                    for (int jj = 0; jj < 4; ++jj) {
                        float r = sc[jj];
                        r = fmaf(b4.x, fabsf(fsv.x + fdv[jj].x), r);
                        r = fmaf(b4.y, fabsf(fsv.y + fdv[jj].y), r);
                        r = fmaf(b4.z, fabsf(fsv.z + fdv[jj].z), r);
                        r = fmaf(b4.w, fabsf(fsv.w + fdv[jj].w), r);
                        sc[jj] = r;
                    }
                }
            }
            if (dh) {
                #pragma unroll
                for (int ii = 0; ii < 4; ++ii)
                    *(float4*)&sm.a.st2[(iT + 16 * ii) * 68 + j0D] = scq[ii];
            }
        }
        __syncthreads();
        if (act && !dh) {
            float cdj[4];
            #pragma unroll
            for (int jj = 0; jj < 4; ++jj)
                cdj[jj] = sm.a.redm[128 + j0D + jj] + sm.a.redm[192 + j0D + jj];
            #pragma unroll
            for (int ii = 0; ii < 4; ++ii) {
                const int i = iT + 16 * ii;
                const float4 p2 = *(const float4*)&sm.a.st2[i * 68 + j0D];
                const float csl = sm.a.redm[i] + sm.a.redm[64 + i];
                const float* sc = (const float*)&scq[ii];
                const float* pp = (const float*)&p2;
                #pragma unroll
                for (int jj = 0; jj < 4; ++jj)
                    sm.a.stT[(j0D + jj) * 68 + i] = sc[jj] + pp[jj] + csl + cdj[jj];
            }
        }
    }
    __syncthreads();

    // ------- phase E: row softmax on t<512, 8 threads per j --------------
    if (t < 512) {
        const int j   = t >> 3;          // row
        const int sub = t & 7;           // i-slice: 8 consecutive i
        float* rp = &sm.a.stT[j * 68 + sub * 8];
        float4 r0 = *(const float4*)(rp);
        float4 r1 = *(const float4*)(rp + 4);
        float mx = fmaxf(fmaxf(fmaxf(r0.x, r0.y), fmaxf(r0.z, r0.w)),
                         fmaxf(fmaxf(r1.x, r1.y), fmaxf(r1.z, r1.w)));
        #pragma unroll
        for (int o = 1; o < 8; o <<= 1) mx = fmaxf(mx, __shfl_xor(mx, o));
        float4 e0, e1;
        e0.x = __expf(r0.x - mx); e0.y = __expf(r0.y - mx);
        e0.z = __expf(r0.z - mx); e0.w = __expf(r0.w - mx);
        e1.x = __expf(r1.x - mx); e1.y = __expf(r1.y - mx);
        e1.z = __expf(r1.z - mx); e1.w = __expf(r1.w - mx);
        float s = e0.x + e0.y + e0.z + e0.w + e1.x + e1.y + e1.z + e1.w;
        #pragma unroll
        for (int o = 1; o < 8; o <<= 1) s += __shfl_xor(s, o);
        *(float4*)(rp)     = e0;
        *(float4*)(rp + 4) = e1;
        if (sub == 0) sm.a.invl[j] = 0.25f / s;   // head-mean folded in
    }
    __syncthreads();

    // ---- phase F: aggregation on t<512, 4j x 8d, dense sector atomics ---
    {
        const bool act = t < 512;
        const int ih  = (t >> 8) & 1;
        const int rem = t & 255;
        const int jT  = rem & 15;
        const int dgF = rem >> 4;
        const int dF  = dgF * 4;
        const int iBase = ih * 32;

        float ag[4][8] = {};             // [jj][dd] dd<4: dF+dd ; else dF+64+dd-4
        if (act) {
            #pragma unroll 2
            for (int i2 = 0; i2 < 32; i2 += 4) {
                float4 pq[4];            // [jj] = p over 4 consecutive i
                #pragma unroll
                for (int jj = 0; jj < 4; ++jj)
                    pq[jj] = *(const float4*)&sm.a.stT[(jT + 16 * jj) * 68 + iBase + i2];
                #pragma unroll
                for (int u = 0; u < 4; ++u) {
                    const int i = iBase + i2 + u;
                    const float4 f0 = *(const float4*)&sm.a.fsl[i * 132 + dF];
                    const float4 f1 = *(const float4*)&sm.a.fsl[i * 132 + dF + 64];
                    #pragma unroll
                    for (int jj = 0; jj < 4; ++jj) {
                        const float p = ((const float*)&pq[jj])[u];
                        ag[jj][0] = fmaf(p, f0.x, ag[jj][0]);
                        ag[jj][1] = fmaf(p, f0.y, ag[jj][1]);
                        ag[jj][2] = fmaf(p, f0.z, ag[jj][2]);
                        ag[jj][3] = fmaf(p, f0.w, ag[jj][3]);
                        ag[jj][4] = fmaf(p, f1.x, ag[jj][4]);
                        ag[jj][5] = fmaf(p, f1.y, ag[jj][5]);
                        ag[jj][6] = fmaf(p, f1.z, ag[jj][6]);
                        ag[jj][7] = fmaf(p, f1.w, ag[jj][7]);
                    }
                }
            }
            if (ih) {
                #pragma unroll
                for (int jj = 0; jj < 4; ++jj) {
                    float4 a0 = {ag[jj][0], ag[jj][1], ag[jj][2], ag[jj][3]};
                    float4 a1 = {ag[jj][4], ag[jj][5], ag[jj][6], ag[jj][7]};
                    *(float4*)&sm.a.xfer[rem * 36 + jj * 8]     = a0;
                    *(float4*)&sm.a.xfer[rem * 36 + jj * 8 + 4] = a1;
                }
            }
        }
        __syncthreads();
        if (act && !ih) {
            float* ob = out + (size_t)b * OW * FF;
            #pragma unroll
            for (int jj = 0; jj < 4; ++jj) {
                const float4 a0 = *(const float4*)&sm.a.xfer[rem * 36 + jj * 8];
                const float4 a1 = *(const float4*)&sm.a.xfer[rem * 36 + jj * 8 + 4];
                const float iv = sm.a.invl[jT + 16 * jj];
                const int j = jT + 16 * jj;
                atomicAdd(ob + (size_t)(dF + 0) * FF + j, (ag[jj][0] + a0.x) * iv);
                atomicAdd(ob + (size_t)(dF + 1) * FF + j, (ag[jj][1] + a0.y) * iv);
                atomicAdd(ob + (size_t)(dF + 2) * FF + j, (ag[jj][2] + a0.z) * iv);
                atomicAdd(ob + (size_t)(dF + 3) * FF + j, (ag[jj][3] + a0.w) * iv);
                atomicAdd(ob + (size_t)(dF + 64) * FF + j, (ag[jj][4] + a1.x) * iv);
                atomicAdd(ob + (size_t)(dF + 65) * FF + j, (ag[jj][5] + a1.y) * iv);
                atomicAdd(ob + (size_t)(dF + 66) * FF + j, (ag[jj][6] + a1.z) * iv);
                atomicAdd(ob + (size_t)(dF + 67) * FF + j, (ag[jj][7] + a1.w) * iv);
            }
        }
    }
}

// ---------------------------------------------------------------------------
extern "C" void kernel_launch(void* const* d_in, const int* in_sizes, int n_in,
                              void* d_out, int out_size, void* d_ws, size_t ws_size,
                              hipStream_t stream) {
    const float* x    = (const float*)d_in[0];
    const float* Wsrc = (const float*)d_in[1];
    const float* bsrc = (const float*)d_in[2];
    const float* Wdst = (const float*)d_in[3];
    const float* bdst = (const float*)d_in[4];
    const float* attn = (const float*)d_in[5];

    hipMemsetAsync(d_out, 0, (size_t)out_size, stream);
    gat_fused<<<BB * HH, 1024, 0, stream>>>(x, Wsrc, bsrc, Wdst, bdst, attn,
                                            (float*)d_out);
}

// Round 14
// 104.301 us; speedup vs baseline: 1.0091x; 1.0091x over previous
//
#include <hip/hip_runtime.h>
#include <math.h>

#define BB 64
#define WW 128   // K (input feature dim per node)
#define FF 64    // nodes
#define HH 4
#define OW 128   // D (per-head output dim)

// ---------------------------------------------------------------------------
// Fully fused GAT, v13 = v12 + amdgpu_waves_per_eu(4,4). One-line fix.
// v12 post-mortem: k-split A structure landed (Occupancy 18->34%) but VGPR
// pinned at 64 (allocator defaulted to 8-wave/SIMD target after the
// waves_per_eu pin was dropped at the 1024-thread switch) -> acc+wv spilled
// (WRITE 14.3MB vs 8.2 clean). Same failure class as v3; same repair as v4.
// 1024 thr x 1 blk/CU = 4 waves/SIMD; waves_per_eu(4,4) => 128-VGPR budget;
// A needs ~90-110 -> fits. Everything else byte-identical to v12.
// Failure read: VGPR=128 AND WRITE>=13MB => loop can't fit 128 regs =>
// v9 is the structural optimum.
// ---------------------------------------------------------------------------

struct GemmRegion {
    float wq[2 * 2 * 128 * 68]; // [(kh*256 + m*128 + d)][k 64 pad 68] 139 KB
};
struct AttnRegion {
    float fsl[FF * 132];        // [i][d] pad 132
    float fdl[FF * 132];        // [j][d] pad 132
    float stT[FF * 68];         // [j][i] pad 68  (TRANSPOSED scores)
    float st2[FF * 68];         // [i][j] pad 68  (D partial exchange)
    float A6[OW], B4[OW];       // 0.6*a_d, 0.4*a_d
    float redm[4 * 64];         // C: cs/cd partials
    float invl[64];             // 0.25 / l_j
    float xfer[256 * 36];       // F: i-half partial exchange (36.9 KB)
};
struct ExRegion {               // A-phase kh-partial exchange:
    float pad[FF * 132 * 2];    //   overlays fsl+fdl (NOT touched)
    float ex[512 * 36];         //   overlays stT..xfer (dead at that time)
};
union SMem { GemmRegion g; AttnRegion a; ExRegion e; };

__global__ void __launch_bounds__(1024)
__attribute__((amdgpu_waves_per_eu(4, 4)))
gat_fused(
    const float* __restrict__ x,     // [B][128 k][64 i]
    const float* __restrict__ Wsrc,  // [512][128]
    const float* __restrict__ bsrc,
    const float* __restrict__ Wdst,
    const float* __restrict__ bdst,
    const float* __restrict__ attn,  // [H][128]
    float* __restrict__ out)         // [B][128 d][64 j], pre-zeroed
{
    __shared__ __align__(16) SMem sm;
    __shared__ float bl[2 * 128];

    const int bx = blockIdx.x;
    const int h  = bx & 3;
    const int b  = bx >> 2;
    const int t  = threadIdx.x;

    // ---- phase A map (1024): kh | m | ig(16 x 4 rows) | dg(16 -> 8 d) ----
    // thread: k-half kh, rows i = ig*4..+3 of (m ? fd : fs), d = dg + 16e.
    const int kh   = t >> 9;
    const int rem9 = t & 511;
    const int m    = rem9 >> 8;
    const int ig   = (rem9 >> 4) & 15;
    const int dg   = rem9 & 15;
    const int i0   = ig * 4;

    if (t < 256) bl[t] = (t & 128 ? bdst : bsrc)[h * 128 + (t & 127)];

    const float* xb = x + (size_t)b * (WW * FF);   // [128 k][64 node]

    // ---- stage BOTH W k-halves: 8192 float4, 8 per thread ----
    #pragma unroll
    for (int p = 0; p < 8; ++p) {
        const int idx = p * 1024 + t;           // [kh 2][mm 2][d 128][q 16]
        const int k2 = idx >> 12;
        const int mm = (idx >> 11) & 1;
        const int d  = (idx >> 4) & 127;
        const int q  = idx & 15;
        *(float4*)&sm.g.wq[((k2 << 8) + mm * 128 + d) * 68 + q * 4] =
            *(const float4*)((mm ? Wdst : Wsrc)
                             + (size_t)(h * 128 + d) * WW + k2 * 64 + q * 4);
    }
    __syncthreads();

    float acc[4][8] = {};            // [ii][e]
    {
        const int wbase = (kh << 8) + m * 128 + dg;   // + 16*e
        const float* xk = xb + (size_t)(kh * 64) * FF;
        #pragma unroll 2
        for (int k0 = 0; k0 < 64; k0 += 4) {
            float4 wv[8];
            #pragma unroll
            for (int e = 0; e < 8; ++e)
                wv[e] = *(const float4*)&sm.g.wq[(wbase + 16 * e) * 68 + k0];
            #pragma unroll
            for (int kk = 0; kk < 4; ++kk) {
                const float4 xv = *(const float4*)(xk + (size_t)(k0 + kk) * FF + i0);
                #pragma unroll
                for (int e = 0; e < 8; ++e) {
                    const float wf = ((const float*)&wv[e])[kk];
                    acc[0][e] = fmaf(xv.x, wf, acc[0][e]);
                    acc[1][e] = fmaf(xv.y, wf, acc[1][e]);
                    acc[2][e] = fmaf(xv.z, wf, acc[2][e]);
                    acc[3][e] = fmaf(xv.w, wf, acc[3][e]);
                }
            }
        }
    }
    __syncthreads();   // wq dead

    // ---- kh-partial exchange: kh1 writes ex (stride 36: conflict-free) ----
    if (kh) {
        #pragma unroll
        for (int ii = 0; ii < 4; ++ii) {
            float4 a0 = {acc[ii][0], acc[ii][1], acc[ii][2], acc[ii][3]};
            float4 a1 = {acc[ii][4], acc[ii][5], acc[ii][6], acc[ii][7]};
            *(float4*)&sm.e.ex[rem9 * 36 + ii * 8]     = a0;
            *(float4*)&sm.e.ex[rem9 * 36 + ii * 8 + 4] = a1;
        }
    }
    __syncthreads();

    // ---- phase B: kh0 combines partials + bias -> fsl/fdl ----
    if (!kh) {
        float* dst = m ? sm.a.fdl : sm.a.fsl;
        #pragma unroll
        for (int ii = 0; ii < 4; ++ii) {
            const float4 p0 = *(const float4*)&sm.e.ex[rem9 * 36 + ii * 8];
            const float4 p1 = *(const float4*)&sm.e.ex[rem9 * 36 + ii * 8 + 4];
            const float* pp0 = (const float*)&p0;
            const float* pp1 = (const float*)&p1;
            #pragma unroll
            for (int e = 0; e < 8; ++e) {
                const int d = dg + 16 * e;
                const float pv = (e < 4) ? pp0[e] : pp1[e - 4];
                dst[(i0 + ii) * 132 + d] = acc[ii][e] + pv + bl[m * 128 + d];
            }
        }
    }
    __syncthreads();   // ex dead; A6/B4 area safe to write now

    if (t < 128) {
        const float av = attn[h * OW + t];
        sm.a.A6[t] = 0.6f * av;
        sm.a.B4[t] = 0.4f * av;
    }
    __syncthreads();

    // --------- phase C: cs/cd partials (256 threads, 2 halves each) ------
    if (t < 256) {
        const int i = t & 63, sel = t >> 6;
        const float* src = (sel < 2 ? sm.a.fsl : sm.a.fdl) + i * 132 + (sel & 1) * 64;
        const float* a6  = sm.a.A6 + (sel & 1) * 64;
        float s = 0.0f;
        #pragma unroll
        for (int c = 0; c < 16; ++c) {
            float4 fv = *(const float4*)&src[c * 4];
            float4 av = *(const float4*)&a6[c * 4];
            s = fmaf(fv.x, av.x, fmaf(fv.y, av.y, fmaf(fv.z, av.z, fmaf(fv.w, av.w, s))));
        }
        sm.a.redm[sel * 64 + i] = s;
    }
    __syncthreads();

    // -------- phase D: scores on t<512, 2-D tile 4i x 4j, d-split --------
    {
        const bool act = t < 512;
        const int dh  = (t >> 8) & 1;
        const int rem = t & 255;
        const int iT  = rem & 15;
        const int j0D = (rem >> 4) * 4;
        float4 scq[4];                   // [ii]; components = jj
        scq[0] = scq[1] = scq[2] = scq[3] = float4{0.f, 0.f, 0.f, 0.f};
        if (act) {
            const int cBase = dh * 16;
            #pragma unroll 4
            for (int c = 0; c < 16; ++c) {
                const int dd0 = (cBase + c) * 4;
                const float4 b4 = *(const float4*)&sm.a.B4[dd0];
                float4 fdv[4];
                #pragma unroll
                for (int jj = 0; jj < 4; ++jj)
                    fdv[jj] = *(const float4*)&sm.a.fdl[(j0D + jj) * 132 + dd0];
                #pragma unroll
                for (int ii = 0; ii < 4; ++ii) {
                    const float4 fsv =
                        *(const float4*)&sm.a.fsl[(iT + 16 * ii) * 132 + dd0];
                    float* sc = (float*)&scq[ii];
                    #pragma unroll
                    for (int jj = 0; jj < 4; ++jj) {
                        float r = sc[jj];
                        r = fmaf(b4.x, fabsf(fsv.x + fdv[jj].x), r);
                        r = fmaf(b4.y, fabsf(fsv.y + fdv[jj].y), r);
                        r = fmaf(b4.z, fabsf(fsv.z + fdv[jj].z), r);
                        r = fmaf(b4.w, fabsf(fsv.w + fdv[jj].w), r);
                        sc[jj] = r;
                    }
                }
            }
            if (dh) {
                #pragma unroll
                for (int ii = 0; ii < 4; ++ii)
                    *(float4*)&sm.a.st2[(iT + 16 * ii) * 68 + j0D] = scq[ii];
            }
        }
        __syncthreads();
        if (act && !dh) {
            float cdj[4];
            #pragma unroll
            for (int jj = 0; jj < 4; ++jj)
                cdj[jj] = sm.a.redm[128 + j0D + jj] + sm.a.redm[192 + j0D + jj];
            #pragma unroll
            for (int ii = 0; ii < 4; ++ii) {
                const int i = iT + 16 * ii;
                const float4 p2 = *(const float4*)&sm.a.st2[i * 68 + j0D];
                const float csl = sm.a.redm[i] + sm.a.redm[64 + i];
                const float* sc = (const float*)&scq[ii];
                const float* pp = (const float*)&p2;
                #pragma unroll
                for (int jj = 0; jj < 4; ++jj)
                    sm.a.stT[(j0D + jj) * 68 + i] = sc[jj] + pp[jj] + csl + cdj[jj];
            }
        }
    }
    __syncthreads();

    // ------- phase E: row softmax on t<512, 8 threads per j --------------
    if (t < 512) {
        const int j   = t >> 3;          // row
        const int sub = t & 7;           // i-slice: 8 consecutive i
        float* rp = &sm.a.stT[j * 68 + sub * 8];
        float4 r0 = *(const float4*)(rp);
        float4 r1 = *(const float4*)(rp + 4);
        float mx = fmaxf(fmaxf(fmaxf(r0.x, r0.y), fmaxf(r0.z, r0.w)),
                         fmaxf(fmaxf(r1.x, r1.y), fmaxf(r1.z, r1.w)));
        #pragma unroll
        for (int o = 1; o < 8; o <<= 1) mx = fmaxf(mx, __shfl_xor(mx, o));
        float4 e0, e1;
        e0.x = __expf(r0.x - mx); e0.y = __expf(r0.y - mx);
        e0.z = __expf(r0.z - mx); e0.w = __expf(r0.w - mx);
        e1.x = __expf(r1.x - mx); e1.y = __expf(r1.y - mx);
        e1.z = __expf(r1.z - mx); e1.w = __expf(r1.w - mx);
        float s = e0.x + e0.y + e0.z + e0.w + e1.x + e1.y + e1.z + e1.w;
        #pragma unroll
        for (int o = 1; o < 8; o <<= 1) s += __shfl_xor(s, o);
        *(float4*)(rp)     = e0;
        *(float4*)(rp + 4) = e1;
        if (sub == 0) sm.a.invl[j] = 0.25f / s;   // head-mean folded in
    }
    __syncthreads();

    // ---- phase F: aggregation on t<512, 4j x 8d, dense sector atomics ---
    {
        const bool act = t < 512;
        const int ih  = (t >> 8) & 1;
        const int rem = t & 255;
        const int jT  = rem & 15;
        const int dgF = rem >> 4;
        const int dF  = dgF * 4;
        const int iBase = ih * 32;

        float ag[4][8] = {};             // [jj][dd] dd<4: dF+dd ; else dF+64+dd-4
        if (act) {
            #pragma unroll 2
            for (int i2 = 0; i2 < 32; i2 += 4) {
                float4 pq[4];            // [jj] = p over 4 consecutive i
                #pragma unroll
                for (int jj = 0; jj < 4; ++jj)
                    pq[jj] = *(const float4*)&sm.a.stT[(jT + 16 * jj) * 68 + iBase + i2];
                #pragma unroll
                for (int u = 0; u < 4; ++u) {
                    const int i = iBase + i2 + u;
                    const float4 f0 = *(const float4*)&sm.a.fsl[i * 132 + dF];
                    const float4 f1 = *(const float4*)&sm.a.fsl[i * 132 + dF + 64];
                    #pragma unroll
                    for (int jj = 0; jj < 4; ++jj) {
                        const float p = ((const float*)&pq[jj])[u];
                        ag[jj][0] = fmaf(p, f0.x, ag[jj][0]);
                        ag[jj][1] = fmaf(p, f0.y, ag[jj][1]);
                        ag[jj][2] = fmaf(p, f0.z, ag[jj][2]);
                        ag[jj][3] = fmaf(p, f0.w, ag[jj][3]);
                        ag[jj][4] = fmaf(p, f1.x, ag[jj][4]);
                        ag[jj][5] = fmaf(p, f1.y, ag[jj][5]);
                        ag[jj][6] = fmaf(p, f1.z, ag[jj][6]);
                        ag[jj][7] = fmaf(p, f1.w, ag[jj][7]);
                    }
                }
            }
            if (ih) {
                #pragma unroll
                for (int jj = 0; jj < 4; ++jj) {
                    float4 a0 = {ag[jj][0], ag[jj][1], ag[jj][2], ag[jj][3]};
                    float4 a1 = {ag[jj][4], ag[jj][5], ag[jj][6], ag[jj][7]};
                    *(float4*)&sm.a.xfer[rem * 36 + jj * 8]     = a0;
                    *(float4*)&sm.a.xfer[rem * 36 + jj * 8 + 4] = a1;
                }
            }
        }
        __syncthreads();
        if (act && !ih) {
            float* ob = out + (size_t)b * OW * FF;
            #pragma unroll
            for (int jj = 0; jj < 4; ++jj) {
                const float4 a0 = *(const float4*)&sm.a.xfer[rem * 36 + jj * 8];
                const float4 a1 = *(const float4*)&sm.a.xfer[rem * 36 + jj * 8 + 4];
                const float iv = sm.a.invl[jT + 16 * jj];
                const int j = jT + 16 * jj;
                atomicAdd(ob + (size_t)(dF + 0) * FF + j, (ag[jj][0] + a0.x) * iv);
                atomicAdd(ob + (size_t)(dF + 1) * FF + j, (ag[jj][1] + a0.y) * iv);
                atomicAdd(ob + (size_t)(dF + 2) * FF + j, (ag[jj][2] + a0.z) * iv);
                atomicAdd(ob + (size_t)(dF + 3) * FF + j, (ag[jj][3] + a0.w) * iv);
                atomicAdd(ob + (size_t)(dF + 64) * FF + j, (ag[jj][4] + a1.x) * iv);
                atomicAdd(ob + (size_t)(dF + 65) * FF + j, (ag[jj][5] + a1.y) * iv);
                atomicAdd(ob + (size_t)(dF + 66) * FF + j, (ag[jj][6] + a1.z) * iv);
                atomicAdd(ob + (size_t)(dF + 67) * FF + j, (ag[jj][7] + a1.w) * iv);
            }
        }
    }
}

// ---------------------------------------------------------------------------
extern "C" void kernel_launch(void* const* d_in, const int* in_sizes, int n_in,
                              void* d_out, int out_size, void* d_ws, size_t ws_size,
                              hipStream_t stream) {
    const float* x    = (const float*)d_in[0];
    const float* Wsrc = (const float*)d_in[1];
    const float* bsrc = (const float*)d_in[2];
    const float* Wdst = (const float*)d_in[3];
    const float* bdst = (const float*)d_in[4];
    const float* attn = (const float*)d_in[5];

    hipMemsetAsync(d_out, 0, (size_t)out_size, stream);
    gat_fused<<<BB * HH, 1024, 0, stream>>>(x, Wsrc, bsrc, Wdst, bdst, attn,
                                            (float*)d_out);
}

// Round 15
// 100.627 us; speedup vs baseline: 1.0459x; 1.0365x over previous
//
#include <hip/hip_runtime.h>
#include <math.h>

#define BB 64
#define WW 128   // K (input feature dim per node)
#define FF 64    // nodes
#define HH 4
#define OW 128   // D (per-head output dim)

// ---------------------------------------------------------------------------
// Fully fused GAT, FINAL = v9 restored (best measured: kernel 41.6 us,
// dur_us 100.13, VGPR 88, WRITE 8.2MB, conflicts 65K).
// Session ledger:
//  - Fusion (v1): killed 40MB intermediates + ws poison fill; 114.9 -> 106.6
//  - Occupancy 1024thr (v2): 49.8 -> 45.4 us kernel
//  - LDS-slot economy + no-spill (v4): 45.4 -> 46.5 (v3 spill lesson)
//  - Dense sector atomics + stT transpose (v7): WRITE 65 -> 13.8MB
//  - x-direct-from-global + all-wave A (v8): 44 -> 42.5
//  - Single W stage + unroll + parallel E (v9): 42.5 -> 41.6
// Closed avenues (measured): W-from-global (16 lines/instr, v10 91us);
// 8i tile (2x x-loads + spill, v11 56us); k-split A (1024-thread blocks
// are hard-capped at 64 VGPR by the compiler regardless of
// amdgpu_waves_per_eu -> forced spill, v12/v13 45.7us).
// Wall: ~50% VALU / ~50% LDS-pipe at 2 waves/SIMD, latency/barrier floor.
// ---------------------------------------------------------------------------

struct GemmRegion {
    float wq[2 * 2 * 128 * 68]; // [(kh*256 + m*128 + d)][k 64 pad 68] 139 KB
};
struct AttnRegion {
    float fsl[FF * 132];        // [i][d] pad 132
    float fdl[FF * 132];        // [j][d] pad 132
    float stT[FF * 68];         // [j][i] pad 68  (TRANSPOSED scores)
    float st2[FF * 68];         // [i][j] pad 68  (D partial exchange)
    float A6[OW], B4[OW];       // 0.6*a_d, 0.4*a_d
    float redm[4 * 64];         // C: cs/cd partials
    float invl[64];             // 0.25 / l_j
    float xfer[256 * 36];       // F: i-half partial exchange (36.9 KB)
};
union SMem { GemmRegion g; AttnRegion a; };

__global__ void __launch_bounds__(512)
__attribute__((amdgpu_waves_per_eu(2, 2)))
gat_fused(
    const float* __restrict__ x,     // [B][128 k][64 i]
    const float* __restrict__ Wsrc,  // [512][128]
    const float* __restrict__ bsrc,
    const float* __restrict__ Wdst,
    const float* __restrict__ bdst,
    const float* __restrict__ attn,  // [H][128]
    float* __restrict__ out)         // [B][128 d][64 j], pre-zeroed
{
    __shared__ __align__(16) SMem sm;
    __shared__ float bl[2 * 128];

    const int bx = blockIdx.x;
    const int h  = bx & 3;
    const int b  = bx >> 2;
    const int t  = threadIdx.x;

    // ---- phase A thread map (ALL 512): m | ig(16 x 4 rows) | dg(16) ----
    // outputs: row i = ig*4 .. +3 of (m ? fd : fs), d = dg + 16*e (e = 0..7)
    const int m  = t >> 8;
    const int ig = (t >> 4) & 15;
    const int dg = t & 15;
    const int i0 = ig * 4;

    if (t < 256) bl[t] = (t & 128 ? bdst : bsrc)[h * 128 + (t & 127)];

    const float* xb = x + (size_t)b * (WW * FF);   // [128 k][64 node]

    // ---- stage BOTH W k-halves: 8192 float4, 16 per thread ----
    #pragma unroll
    for (int p = 0; p < 16; ++p) {
        const int idx = p * 512 + t;            // [kh 2][mm 2][d 128][q 16]
        const int kh = idx >> 12;
        const int mm = (idx >> 11) & 1;
        const int d  = (idx >> 4) & 127;
        const int q  = idx & 15;
        *(float4*)&sm.g.wq[((kh << 8) + mm * 128 + d) * 68 + q * 4] =
            *(const float4*)((mm ? Wdst : Wsrc)
                             + (size_t)(h * 128 + d) * WW + kh * 64 + q * 4);
    }
    __syncthreads();

    float acc[4][8] = {};            // [ii][e]
    {
        const int wrow = m * 128 + dg;          // + 16*e
        #pragma unroll 2
        for (int k0 = 0; k0 < 128; k0 += 4) {
            const int kq = k0 >> 6;             // which k-half
            const int kw = k0 & 63;             // k within half
            float4 wv[8];
            #pragma unroll
            for (int e = 0; e < 8; ++e)
                wv[e] = *(const float4*)&sm.g.wq[((kq << 8) + wrow + 16 * e) * 68 + kw];
            #pragma unroll
            for (int kk = 0; kk < 4; ++kk) {
                const float4 xv = *(const float4*)(xb + (size_t)(k0 + kk) * FF + i0);
                #pragma unroll
                for (int e = 0; e < 8; ++e) {
                    const float wf = ((const float*)&wv[e])[kk];
                    acc[0][e] = fmaf(xv.x, wf, acc[0][e]);
                    acc[1][e] = fmaf(xv.y, wf, acc[1][e]);
                    acc[2][e] = fmaf(xv.z, wf, acc[2][e]);
                    acc[3][e] = fmaf(xv.w, wf, acc[3][e]);
                }
            }
        }
    }
    __syncthreads();   // GEMM region dead; attn region may now be written

    // ------------- phase B: acc+bias -> fsl/fdl, stage A6/B4 -------------
    {
        float* dst = m ? sm.a.fdl : sm.a.fsl;
        #pragma unroll
        for (int e = 0; e < 8; ++e) {
            const int d = dg + 16 * e;
            const float bv = bl[m * 128 + d];
            #pragma unroll
            for (int ii = 0; ii < 4; ++ii)
                dst[(i0 + ii) * 132 + d] = acc[ii][e] + bv;
        }
    }
    if (t < 128) {
        const float av = attn[h * OW + t];
        sm.a.A6[t] = 0.6f * av;
        sm.a.B4[t] = 0.4f * av;
    }
    __syncthreads();

    // --------- phase C: cs/cd partials (256 threads, 2 halves each) ------
    // redm[sel*64+i]: sel 0,1 = fs halves; 2,3 = fd halves. Summed in D.
    if (t < 256) {
        const int i = t & 63, sel = t >> 6;
        const float* src = (sel < 2 ? sm.a.fsl : sm.a.fdl) + i * 132 + (sel & 1) * 64;
        const float* a6  = sm.a.A6 + (sel & 1) * 64;
        float s = 0.0f;
        #pragma unroll
        for (int c = 0; c < 16; ++c) {
            float4 fv = *(const float4*)&src[c * 4];
            float4 av = *(const float4*)&a6[c * 4];
            s = fmaf(fv.x, av.x, fmaf(fv.y, av.y, fmaf(fv.z, av.z, fmaf(fv.w, av.w, s))));
        }
        sm.a.redm[sel * 64 + i] = s;
    }
    __syncthreads();

    // -------- phase D: scores, 2-D tile 4i x 4j, d-halves via st2 --------
    // thread = (dh = t>>8, iT = t&15 -> i = iT+16*ii, jg -> 4 consecutive j)
    {
        const int dh  = t >> 8;
        const int rem = t & 255;
        const int iT  = rem & 15;
        const int j0D = (rem >> 4) * 4;
        float4 scq[4];                   // [ii]; components = jj
        scq[0] = scq[1] = scq[2] = scq[3] = float4{0.f, 0.f, 0.f, 0.f};
        const int cBase = dh * 16;
        #pragma unroll 4
        for (int c = 0; c < 16; ++c) {
            const int dd0 = (cBase + c) * 4;
            const float4 b4 = *(const float4*)&sm.a.B4[dd0];
            float4 fdv[4];
            #pragma unroll
            for (int jj = 0; jj < 4; ++jj)
                fdv[jj] = *(const float4*)&sm.a.fdl[(j0D + jj) * 132 + dd0];
            #pragma unroll
            for (int ii = 0; ii < 4; ++ii) {
                const float4 fsv =
                    *(const float4*)&sm.a.fsl[(iT + 16 * ii) * 132 + dd0];
                float* sc = (float*)&scq[ii];
                #pragma unroll
                for (int jj = 0; jj < 4; ++jj) {
                    float r = sc[jj];
                    r = fmaf(b4.x, fabsf(fsv.x + fdv[jj].x), r);
                    r = fmaf(b4.y, fabsf(fsv.y + fdv[jj].y), r);
                    r = fmaf(b4.z, fabsf(fsv.z + fdv[jj].z), r);
                    r = fmaf(b4.w, fabsf(fsv.w + fdv[jj].w), r);
                    sc[jj] = r;
                }
            }
        }
        if (dh) {
            #pragma unroll
            for (int ii = 0; ii < 4; ++ii)
                *(float4*)&sm.a.st2[(iT + 16 * ii) * 68 + j0D] = scq[ii];
        }
        __syncthreads();
        if (!dh) {
            float cdj[4];
            #pragma unroll
            for (int jj = 0; jj < 4; ++jj)
                cdj[jj] = sm.a.redm[128 + j0D + jj] + sm.a.redm[192 + j0D + jj];
            #pragma unroll
            for (int ii = 0; ii < 4; ++ii) {
                const int i = iT + 16 * ii;
                const float4 p2 = *(const float4*)&sm.a.st2[i * 68 + j0D];
                const float csl = sm.a.redm[i] + sm.a.redm[64 + i];
                const float* sc = (const float*)&scq[ii];
                const float* pp = (const float*)&p2;
                // transposed store: stT[j][i]
                #pragma unroll
                for (int jj = 0; jj < 4; ++jj)
                    sm.a.stT[(j0D + jj) * 68 + i] = sc[jj] + pp[jj] + csl + cdj[jj];
            }
        }
    }
    __syncthreads();

    // ------- phase E: row softmax, 8 threads per j (all 512 threads) -----
    {
        const int j   = t >> 3;          // row
        const int sub = t & 7;           // i-slice: 8 consecutive i
        float* rp = &sm.a.stT[j * 68 + sub * 8];
        float4 r0 = *(const float4*)(rp);
        float4 r1 = *(const float4*)(rp + 4);
        float mx = fmaxf(fmaxf(fmaxf(r0.x, r0.y), fmaxf(r0.z, r0.w)),
                         fmaxf(fmaxf(r1.x, r1.y), fmaxf(r1.z, r1.w)));
        #pragma unroll
        for (int o = 1; o < 8; o <<= 1) mx = fmaxf(mx, __shfl_xor(mx, o));
        float4 e0, e1;
        e0.x = __expf(r0.x - mx); e0.y = __expf(r0.y - mx);
        e0.z = __expf(r0.z - mx); e0.w = __expf(r0.w - mx);
        e1.x = __expf(r1.x - mx); e1.y = __expf(r1.y - mx);
        e1.z = __expf(r1.z - mx); e1.w = __expf(r1.w - mx);
        float s = e0.x + e0.y + e0.z + e0.w + e1.x + e1.y + e1.z + e1.w;
        #pragma unroll
        for (int o = 1; o < 8; o <<= 1) s += __shfl_xor(s, o);
        *(float4*)(rp)     = e0;
        *(float4*)(rp + 4) = e1;
        if (sub == 0) sm.a.invl[j] = 0.25f / s;   // head-mean folded in
    }
    __syncthreads();

    // ---- phase F: aggregation 4j x 8d, j strided; dense sector atomics ---
    // thread = (ih = t>>8, jT = rem&15, dgF = rem>>4): j = jT+16*jj,
    // d in {dF..dF+3, dF+64..dF+67}, dF = 4*dgF.
    {
        const int ih  = t >> 8;
        const int rem = t & 255;
        const int jT  = rem & 15;
        const int dgF = rem >> 4;
        const int dF  = dgF * 4;
        const int iBase = ih * 32;

        float ag[4][8] = {};             // [jj][dd] dd<4: dF+dd ; else dF+64+dd-4
        #pragma unroll 2
        for (int i2 = 0; i2 < 32; i2 += 4) {
            float4 pq[4];                // [jj] = p over 4 consecutive i
            #pragma unroll
            for (int jj = 0; jj < 4; ++jj)
                pq[jj] = *(const float4*)&sm.a.stT[(jT + 16 * jj) * 68 + iBase + i2];
            #pragma unroll
            for (int u = 0; u < 4; ++u) {
                const int i = iBase + i2 + u;
                const float4 f0 = *(const float4*)&sm.a.fsl[i * 132 + dF];
                const float4 f1 = *(const float4*)&sm.a.fsl[i * 132 + dF + 64];
                #pragma unroll
                for (int jj = 0; jj < 4; ++jj) {
                    const float p = ((const float*)&pq[jj])[u];
                    ag[jj][0] = fmaf(p, f0.x, ag[jj][0]);
                    ag[jj][1] = fmaf(p, f0.y, ag[jj][1]);
                    ag[jj][2] = fmaf(p, f0.z, ag[jj][2]);
                    ag[jj][3] = fmaf(p, f0.w, ag[jj][3]);
                    ag[jj][4] = fmaf(p, f1.x, ag[jj][4]);
                    ag[jj][5] = fmaf(p, f1.y, ag[jj][5]);
                    ag[jj][6] = fmaf(p, f1.z, ag[jj][6]);
                    ag[jj][7] = fmaf(p, f1.w, ag[jj][7]);
                }
            }
        }

        // i-half combine through LDS (stride 36 floats = 9 quads, free)
        if (ih) {
            #pragma unroll
            for (int jj = 0; jj < 4; ++jj) {
                float4 a0 = {ag[jj][0], ag[jj][1], ag[jj][2], ag[jj][3]};
                float4 a1 = {ag[jj][4], ag[jj][5], ag[jj][6], ag[jj][7]};
                *(float4*)&sm.a.xfer[rem * 36 + jj * 8]     = a0;
                *(float4*)&sm.a.xfer[rem * 36 + jj * 8 + 4] = a1;
            }
        }
        __syncthreads();
        if (!ih) {
            float* ob = out + (size_t)b * OW * FF;
            #pragma unroll
            for (int jj = 0; jj < 4; ++jj) {
                const float4 a0 = *(const float4*)&sm.a.xfer[rem * 36 + jj * 8];
                const float4 a1 = *(const float4*)&sm.a.xfer[rem * 36 + jj * 8 + 4];
                const float iv = sm.a.invl[jT + 16 * jj];
                const int j = jT + 16 * jj;
                atomicAdd(ob + (size_t)(dF + 0) * FF + j, (ag[jj][0] + a0.x) * iv);
                atomicAdd(ob + (size_t)(dF + 1) * FF + j, (ag[jj][1] + a0.y) * iv);
                atomicAdd(ob + (size_t)(dF + 2) * FF + j, (ag[jj][2] + a0.z) * iv);
                atomicAdd(ob + (size_t)(dF + 3) * FF + j, (ag[jj][3] + a0.w) * iv);
                atomicAdd(ob + (size_t)(dF + 64) * FF + j, (ag[jj][4] + a1.x) * iv);
                atomicAdd(ob + (size_t)(dF + 65) * FF + j, (ag[jj][5] + a1.y) * iv);
                atomicAdd(ob + (size_t)(dF + 66) * FF + j, (ag[jj][6] + a1.z) * iv);
                atomicAdd(ob + (size_t)(dF + 67) * FF + j, (ag[jj][7] + a1.w) * iv);
            }
        }
    }
}

// ---------------------------------------------------------------------------
extern "C" void kernel_launch(void* const* d_in, const int* in_sizes, int n_in,
                              void* d_out, int out_size, void* d_ws, size_t ws_size,
                              hipStream_t stream) {
    const float* x    = (const float*)d_in[0];
    const float* Wsrc = (const float*)d_in[1];
    const float* bsrc = (const float*)d_in[2];
    const float* Wdst = (const float*)d_in[3];
    const float* bdst = (const float*)d_in[4];
    const float* attn = (const float*)d_in[5];

    hipMemsetAsync(d_out, 0, (size_t)out_size, stream);
    gat_fused<<<BB * HH, 512, 0, stream>>>(x, Wsrc, bsrc, Wdst, bdst, attn,
                                           (float*)d_out);
}